// Round 8
// baseline (283.743 us; speedup 1.0000x reference)
//
#include <hip/hip_runtime.h>
#include <stdint.h>

// B=8, S=1024, H=1024, NH=16, HD=64
typedef __attribute__((ext_vector_type(8))) __bf16 bf16x8;
typedef __attribute__((ext_vector_type(8))) unsigned short ushortx8;
typedef __attribute__((ext_vector_type(4))) unsigned short ushortx4;
typedef __attribute__((ext_vector_type(4))) short short4v;
typedef __attribute__((ext_vector_type(4))) float floatx4;

#define LOG2E 1.4426950408889634f
#define QSCALE 0.18033688011112043f   // 0.125 * log2e

#define ASYNC16(g, l) __builtin_amdgcn_global_load_lds( \
    (__attribute__((address_space(1))) void*)(g),       \
    (__attribute__((address_space(3))) void*)(l), 16, 0, 0)

__device__ __forceinline__ unsigned short f2bf(float f) {
    unsigned int u = __float_as_uint(f);
    u += 0x7fffu + ((u >> 16) & 1u);   // round-to-nearest-even
    return (unsigned short)(u >> 16);
}

__device__ __forceinline__ floatx4 mfma32(bf16x8 a, bf16x8 b, floatx4 c) {
    return __builtin_amdgcn_mfma_f32_16x16x32_bf16(a, b, c, 0, 0, 0);
}
__device__ __forceinline__ floatx4 mfma16(short4v a, short4v b, floatx4 c) {
    return __builtin_amdgcn_mfma_f32_16x16x16bf16_1k(a, b, c, 0, 0, 0);
}

// ---------------- fp32 -> bf16 converts (hidden + all 4 weights, one launch) --------
__global__ __launch_bounds__(256) void cvt_all(
    const float* __restrict__ hidden,
    const float* __restrict__ Wq, const float* __restrict__ Wk,
    const float* __restrict__ Wv, const float* __restrict__ Wo,
    unsigned short* __restrict__ hid_bf,
    unsigned short* __restrict__ oqkv, unsigned short* __restrict__ oo)
{
    const float* src;
    unsigned short* dst;
    int i;
    if (blockIdx.x < 4096) {
        src = hidden; dst = hid_bf;
        i = blockIdx.x * 256 + threadIdx.x;          // < 1048576
    } else {
        int blk = (blockIdx.x - 4096) >> 9;
        src = (blk == 0) ? Wq : (blk == 1) ? Wk : (blk == 2) ? Wv : Wo;
        dst = (blk == 3) ? oo : oqkv + (size_t)blk * 1048576;
        i = ((blockIdx.x - 4096) & 511) * 256 + threadIdx.x;   // < 131072
    }
    const float4* p = (const float4*)src + (size_t)i * 2;
    float4 a = p[0], b = p[1];
    ushortx8 o;
    o[0] = f2bf(a.x); o[1] = f2bf(a.y); o[2] = f2bf(a.z); o[3] = f2bf(a.w);
    o[4] = f2bf(b.x); o[5] = f2bf(b.y); o[6] = f2bf(b.z); o[7] = f2bf(b.w);
    *((ushortx8*)dst + i) = o;
}

// ---------- shared BK=64 K-loop, 128x128 tile, swizzled LDS ----------
// LDS tile: 128 rows x 64 cols. Phys 16B-chunk p of row r holds logical chunk
// p^(r&7). Fragment read k-step s (k = s*32 + quad*8): phys = (s*4+quad)^(l16&7).
template<bool SWAP>
__device__ __forceinline__ void kloop_bk64(
    const unsigned short* __restrict__ Ag,
    const unsigned short* __restrict__ Wg,
    unsigned short* As, unsigned short* Bs,
    int wm, int wn, int l16, int quad, int t,
    floatx4 acc[4][4])
{
#pragma unroll 1
    for (int k0 = 0; k0 < 1024; k0 += 64) {
        __syncthreads();
#pragma unroll
        for (int i = 0; i < 4; i++) {
            ASYNC16(Ag + (size_t)i * 32 * 1024 + k0, As + i * 2048 + t * 8);
            ASYNC16(Wg + (size_t)i * 32 * 1024 + k0, Bs + i * 2048 + t * 8);
        }
        __syncthreads();
#pragma unroll
        for (int s = 0; s < 2; s++) {
            int pb = ((s * 4 + quad) ^ (l16 & 7)) * 8;
            bf16x8 af[4], bfr[4];
#pragma unroll
            for (int mt = 0; mt < 4; mt++)
                af[mt] = *(const bf16x8*)(As + (wm + mt * 16 + l16) * 64 + pb);
#pragma unroll
            for (int nt = 0; nt < 4; nt++)
                bfr[nt] = *(const bf16x8*)(Bs + (wn + nt * 16 + l16) * 64 + pb);
            if (SWAP) {
#pragma unroll
                for (int ft = 0; ft < 4; ft++)
#pragma unroll
                    for (int st = 0; st < 4; st++)
                        acc[ft][st] = mfma32(bfr[ft], af[st], acc[ft][st]);
            } else {
#pragma unroll
                for (int mt = 0; mt < 4; mt++)
#pragma unroll
                    for (int nt = 0; nt < 4; nt++)
                        acc[mt][nt] = mfma32(af[mt], bfr[nt], acc[mt][nt]);
            }
        }
    }
}

// ---------------- merged QKV GEMM (SWAP compute) ----------------
// grid (64, 24): y<8 Q (prescaled by QSCALE), y<16 K, else V (permuted [b,h,d,s']).
// Linear id = y*64+x -> id%8 = x%8: same-A-tile blocks already share an XCD.
__global__ __launch_bounds__(256) void gemm_qkv(
    const unsigned short* __restrict__ A,   // [8192][1024] bf16
    const unsigned short* __restrict__ W,   // [Wq;Wk;Wv] [3072][1024]
    const float* __restrict__ bq, const float* __restrict__ bk, const float* __restrict__ bv,
    unsigned short* __restrict__ Qo, unsigned short* __restrict__ Ko,
    unsigned short* __restrict__ Vo)
{
    __shared__ unsigned short As[128 * 64];
    __shared__ unsigned short Bs[128 * 64];
    const int t = threadIdx.x;
    const int wave = t >> 6, lane = t & 63;
    const int quad = lane >> 4, l16 = lane & 15;
    const int wm = (wave >> 1) * 64, wn = (wave & 1) * 64;
    const int srow = t >> 3;
    const int scol = ((t & 7) ^ (srow & 7)) * 8;

    const unsigned short* Ag = A + ((size_t)blockIdx.x * 128 + srow) * 1024 + scol;
    const unsigned short* Wg = W + ((size_t)blockIdx.y * 128 + srow) * 1024 + scol;

    floatx4 acc[4][4] = {};
    kloop_bk64<true>(Ag, Wg, As, Bs, wm, wn, l16, quad, t, acc);

    int y = blockIdx.y;
    if (y < 16) {
        // Q/K: [b,h,s,d]; lane owns 4 consecutive d -> 8B stores. Q gets QSCALE.
        const float* bp = (y < 8) ? bq : bk;
        unsigned short* op = (y < 8) ? Qo : Ko;
        float sc = (y < 8) ? QSCALE : 1.0f;
#pragma unroll
        for (int ft = 0; ft < 4; ft++) {
            int featg = (y * 128 + wn + ft * 16 + quad * 4) & 1023;
            float4 b4 = *(const float4*)(bp + featg);
            int h = featg >> 6, d = featg & 63;
#pragma unroll
            for (int st = 0; st < 4; st++) {
                int sg = blockIdx.x * 128 + wm + st * 16 + l16;
                int b = sg >> 10, s = sg & 1023;
                ushortx4 o4;
                o4[0] = f2bf((acc[ft][st][0] + b4.x) * sc);
                o4[1] = f2bf((acc[ft][st][1] + b4.y) * sc);
                o4[2] = f2bf((acc[ft][st][2] + b4.z) * sc);
                o4[3] = f2bf((acc[ft][st][3] + b4.w) * sc);
                *(ushortx4*)(op + (((size_t)(b * 16 + h) * 1024 + s) * 64 + d)) = o4;
            }
        }
    } else {
        // V: [b,h,d,s'] with per-64-window PV-fragment permutation:
        // s = 64a + nt*16 + q*4 + j  ->  s' = 64a + (nt>>1)*32 + q*8 + (nt&1)*4 + j
        // so attn reads [vf(nt), vf(nt+1)] as one 16B chunk.
#pragma unroll
        for (int ft = 0; ft < 4; ft++) {
            int featg = (y * 128 + wn + ft * 16 + quad * 4) & 1023;
            float4 b4 = *(const float4*)(bv + featg);
#pragma unroll
            for (int r = 0; r < 4; r++) {
                int feat = featg + r;
                int h = feat >> 6, d = feat & 63;
                float bias = (r == 0) ? b4.x : (r == 1) ? b4.y : (r == 2) ? b4.z : b4.w;
#pragma unroll
                for (int st = 0; st < 4; st++) {
                    int sg = blockIdx.x * 128 + wm + st * 16 + l16;
                    int b = sg >> 10, s = sg & 1023;
                    int sp = (s & ~63) + (st >> 1) * 32 + (l16 >> 2) * 8 + (st & 1) * 4 + (l16 & 3);
                    Vo[((size_t)(b * 16 + h) * 64 + d) * 1024 + sp] = f2bf(acc[ft][st][r] + bias);
                }
            }
        }
    }
}

// ---------------- flash attention: 64-row Q tile, exp2 path, permuted V ----------
// grid (128, 16): x = head, y = q-tile. Linear id = y*128+x -> id%8 = head%8:
// all 16 q-tiles of one head land on ONE XCD, so K/V (256 KB/head) stay L2-resident
// (~16 live heads x 256 KB ~= 4 MB per-XCD working set vs 32 MB before).
__global__ __launch_bounds__(256) void attn(
    const unsigned short* __restrict__ Q,   // [b,h,s,d] (scaled)
    const unsigned short* __restrict__ Kg,  // [b,h,s,d]
    const unsigned short* __restrict__ Vt,  // [b,h,d,s'] (permuted)
    const float* __restrict__ mask,         // [B][S]
    unsigned short* __restrict__ ctx)       // [B,S,H] bf16
{
    __shared__ unsigned short Qs[64 * 64];
    __shared__ unsigned short Ks[64 * 64];
    __shared__ unsigned short Vs[64 * 64];
    __shared__ float Msall[1024];

    const int t = threadIdx.x;
    const int wave = t >> 6, lane = t & 63, quad = lane >> 4, l16 = lane & 15;
    const int s7 = l16 & 7;
    const int head = blockIdx.x;
    const int b = head >> 4, h = head & 15;
    const int q0 = blockIdx.y * 64;
    const unsigned short* Qh = Q + (size_t)head * 65536;
    const unsigned short* Kh = Kg + (size_t)head * 65536;
    const unsigned short* Vh = Vt + (size_t)head * 65536;

    const int srow = t >> 3;
    const int scol = ((t & 7) ^ (srow & 7)) * 8;

    {   // mask row -> LDS, pre-scaled by log2e
        float4 m4 = *(const float4*)(mask + b * 1024 + t * 4);
        m4.x *= LOG2E; m4.y *= LOG2E; m4.z *= LOG2E; m4.w *= LOG2E;
        *(float4*)(Msall + t * 4) = m4;
    }

#pragma unroll
    for (int i = 0; i < 2; i++)
        ASYNC16(Qh + (size_t)(q0 + i * 32 + srow) * 64 + scol, Qs + i * 2048 + t * 8);
    __syncthreads();

    int qrow = wave * 16 + l16;
    bf16x8 qf0 = *(const bf16x8*)(Qs + qrow * 64 + ((quad ^ s7) * 8));
    bf16x8 qf1 = *(const bf16x8*)(Qs + qrow * 64 + (((4 + quad) ^ s7) * 8));

    float rs_acc = 0.f;
    floatx4 o_acc[4] = {};   // O^T: rows d = dt*16+quad*4+r, col q = l16

    for (int k0 = 0; k0 < 1024; k0 += 64) {
        __syncthreads();
#pragma unroll
        for (int i = 0; i < 2; i++) {
            ASYNC16(Kh + (size_t)(k0 + i * 32 + srow) * 64 + scol, Ks + i * 2048 + t * 8);
            ASYNC16(Vh + (size_t)(i * 32 + srow) * 1024 + k0 + scol, Vs + i * 2048 + t * 8);
        }
        __syncthreads();

        short4v pf[4];
#pragma unroll
        for (int nt = 0; nt < 4; nt++) {
            int krow = nt * 16 + l16;
            bf16x8 kf0 = *(const bf16x8*)(Ks + krow * 64 + ((quad ^ s7) * 8));
            bf16x8 kf1 = *(const bf16x8*)(Ks + krow * 64 + (((4 + quad) ^ s7) * 8));
            floatx4 z = {0.f, 0.f, 0.f, 0.f};
            z = mfma32(kf0, qf0, z);
            z = mfma32(kf1, qf1, z);
            floatx4 mk = *(const floatx4*)(Msall + k0 + nt * 16 + quad * 4);
#pragma unroll
            for (int r = 0; r < 4; r++) {
                float p = exp2f(z[r] + mk[r]);
                rs_acc += p;
                pf[nt][r] = (short)(__float_as_uint(p) >> 16);   // truncate to bf16
            }
        }

        // O^T += V^T P^T; Vs permuted so (nt,nt+1) fragments are one b128 read
#pragma unroll
        for (int dt = 0; dt < 4; dt++) {
            int vrow = dt * 16 + l16;
            ushortx8 v01 = *(const ushortx8*)(Vs + vrow * 64 + ((quad ^ s7) * 8));
            ushortx8 v23 = *(const ushortx8*)(Vs + vrow * 64 + (((4 + quad) ^ s7) * 8));
            short4v vf0 = {(short)v01[0], (short)v01[1], (short)v01[2], (short)v01[3]};
            short4v vf1 = {(short)v01[4], (short)v01[5], (short)v01[6], (short)v01[7]};
            short4v vf2 = {(short)v23[0], (short)v23[1], (short)v23[2], (short)v23[3]};
            short4v vf3 = {(short)v23[4], (short)v23[5], (short)v23[6], (short)v23[7]};
            o_acc[dt] = mfma16(vf0, pf[0], o_acc[dt]);
            o_acc[dt] = mfma16(vf1, pf[1], o_acc[dt]);
            o_acc[dt] = mfma16(vf2, pf[2], o_acc[dt]);
            o_acc[dt] = mfma16(vf3, pf[3], o_acc[dt]);
        }
    }

    // l reduction across quads (cols of S^T partitioned by quad)
    rs_acc += __shfl_xor(rs_acc, 16);
    rs_acc += __shfl_xor(rs_acc, 32);
    float inv_l = 1.0f / rs_acc;

    int qg = q0 + wave * 16 + l16;
#pragma unroll
    for (int dt = 0; dt < 4; dt++) {
        ushortx4 o4;
#pragma unroll
        for (int r = 0; r < 4; r++) o4[r] = f2bf(o_acc[dt][r] * inv_l);
        *(ushortx4*)(ctx + ((size_t)(b * 1024 + qg)) * 1024 + h * 64 + dt * 16 + quad * 4) = o4;
    }
}

// ---------------- out-proj GEMM + bias + residual -> x (bf16) ----------------
__global__ __launch_bounds__(256) void gemm_proj(
    const unsigned short* __restrict__ A,   // ctx bf16 [8192][1024]
    const unsigned short* __restrict__ W,   // Wo bf16 [1024][1024]
    const float* __restrict__ bo,
    const float* __restrict__ resid,        // hidden fp32 [8192][1024]
    unsigned short* __restrict__ X)         // bf16 [8192][1024]
{
    __shared__ unsigned short As[128 * 64];
    __shared__ unsigned short Bs[128 * 64];
    const int t = threadIdx.x;
    const int wave = t >> 6, lane = t & 63;
    const int quad = lane >> 4, l16 = lane & 15;
    const int wm = (wave >> 1) * 64, wn = (wave & 1) * 64;
    const int srow = t >> 3;
    const int scol = ((t & 7) ^ (srow & 7)) * 8;

    const unsigned short* Ag = A + ((size_t)blockIdx.x * 128 + srow) * 1024 + scol;
    const unsigned short* Wg = W + ((size_t)blockIdx.y * 128 + srow) * 1024 + scol;

    floatx4 acc[4][4] = {};
    kloop_bk64<false>(Ag, Wg, As, Bs, wm, wn, l16, quad, t, acc);

#pragma unroll
    for (int nt = 0; nt < 4; nt++) {
        int gn = blockIdx.y * 128 + wn + nt * 16 + l16;
        float bias = bo[gn];
#pragma unroll
        for (int mt = 0; mt < 4; mt++) {
#pragma unroll
            for (int r = 0; r < 4; r++) {
                int gm = blockIdx.x * 128 + wm + mt * 16 + quad * 4 + r;
                size_t off = (size_t)gm * 1024 + gn;
                X[off] = f2bf(acc[mt][nt][r] + bias + resid[off]);
            }
        }
    }
}

// ---------------- LayerNorm: one block per token row (bf16 in, fp32 out) ------------
__global__ __launch_bounds__(256) void ln_k(const unsigned short* __restrict__ X,
                                            const float* __restrict__ g,
                                            const float* __restrict__ be,
                                            float* __restrict__ out)
{
    int row = blockIdx.x;
    int t = threadIdx.x;
    const unsigned short* xr = X + (size_t)row * 1024;
    ushortx4 xb = *(const ushortx4*)(xr + t * 4);
    float4 v;
    v.x = __uint_as_float((unsigned)xb[0] << 16);
    v.y = __uint_as_float((unsigned)xb[1] << 16);
    v.z = __uint_as_float((unsigned)xb[2] << 16);
    v.w = __uint_as_float((unsigned)xb[3] << 16);
    float s = v.x + v.y + v.z + v.w;
    float ss = v.x * v.x + v.y * v.y + v.z * v.z + v.w * v.w;
    for (int off = 1; off < 64; off <<= 1) {
        s += __shfl_xor(s, off);
        ss += __shfl_xor(ss, off);
    }
    __shared__ float red[8];
    int wave = t >> 6, lane = t & 63;
    if (lane == 0) { red[wave] = s; red[4 + wave] = ss; }
    __syncthreads();
    s = red[0] + red[1] + red[2] + red[3];
    ss = red[4] + red[5] + red[6] + red[7];
    float mu = s * (1.f / 1024.f);
    float var = ss * (1.f / 1024.f) - mu * mu;
    float inv = rsqrtf(var + 1e-12f);
    float4 gv = *(const float4*)(g + t * 4);
    float4 bv = *(const float4*)(be + t * 4);
    float4 o;
    o.x = (v.x - mu) * inv * gv.x + bv.x;
    o.y = (v.y - mu) * inv * gv.y + bv.y;
    o.z = (v.z - mu) * inv * gv.z + bv.z;
    o.w = (v.w - mu) * inv * gv.w + bv.w;
    *(float4*)(out + (size_t)row * 1024 + t * 4) = o;
}

extern "C" void kernel_launch(void* const* d_in, const int* in_sizes, int n_in,
                              void* d_out, int out_size, void* d_ws, size_t ws_size,
                              hipStream_t stream)
{
    const float* hidden = (const float*)d_in[0];
    const float* mask   = (const float*)d_in[1];
    const float* Wq = (const float*)d_in[2];
    const float* bq = (const float*)d_in[3];
    const float* Wk = (const float*)d_in[4];
    const float* bk = (const float*)d_in[5];
    const float* Wv = (const float*)d_in[6];
    const float* bv = (const float*)d_in[7];
    const float* Wo = (const float*)d_in[8];
    const float* bo = (const float*)d_in[9];
    const float* gamma = (const float*)d_in[10];
    const float* beta  = (const float*)d_in[11];
    float* out = (float*)d_out;

    char* ws = (char*)d_ws;
    // layout (bytes): hid_bf 16M | wqkv_bf 6M | wo_bf 2M | vt_bf 16M | ctx_bf 16M | q_bf 16M | k_bf 16M
    // x (bf16, 16M) aliases q_bf (dead after attn). total 88M.
    unsigned short* hid_bf  = (unsigned short*)(ws + 0);
    unsigned short* wqkv_bf = (unsigned short*)(ws + 16777216);
    unsigned short* wo_bf   = (unsigned short*)(ws + 23068672);
    unsigned short* vt_bf   = (unsigned short*)(ws + 25165824);
    unsigned short* ctx_bf  = (unsigned short*)(ws + 41943040);
    unsigned short* q_bf    = (unsigned short*)(ws + 58720256);
    unsigned short* k_bf    = (unsigned short*)(ws + 75497472);
    unsigned short* x_bf    = (unsigned short*)(ws + 58720256);

    cvt_all<<<6144, 256, 0, stream>>>(hidden, Wq, Wk, Wv, Wo, hid_bf, wqkv_bf, wo_bf);

    gemm_qkv<<<dim3(64, 24), 256, 0, stream>>>(hid_bf, wqkv_bf, bq, bk, bv, q_bf, k_bf, vt_bf);
    attn<<<dim3(128, 16), 256, 0, stream>>>(q_bf, k_bf, vt_bf, mask, ctx_bf);
    gemm_proj<<<dim3(64, 8), 256, 0, stream>>>(ctx_bf, wo_bf, bo, hidden, x_bf);
    ln_k<<<8192, 256, 0, stream>>>(x_bf, gamma, beta, out);
}

// Round 9
// 270.948 us; speedup vs baseline: 1.0472x; 1.0472x over previous
//
#include <hip/hip_runtime.h>
#include <stdint.h>

// B=8, S=1024, H=1024, NH=16, HD=64
typedef __attribute__((ext_vector_type(8))) __bf16 bf16x8;
typedef __attribute__((ext_vector_type(8))) unsigned short ushortx8;
typedef __attribute__((ext_vector_type(4))) unsigned short ushortx4;
typedef __attribute__((ext_vector_type(4))) short short4v;
typedef __attribute__((ext_vector_type(4))) float floatx4;

#define LOG2E 1.4426950408889634f
#define QSCALE 0.18033688011112043f   // 0.125 * log2e

#define ASYNC16(g, l) __builtin_amdgcn_global_load_lds( \
    (__attribute__((address_space(1))) void*)(g),       \
    (__attribute__((address_space(3))) void*)(l), 16, 0, 0)

__device__ __forceinline__ unsigned short f2bf(float f) {
    unsigned int u = __float_as_uint(f);
    u += 0x7fffu + ((u >> 16) & 1u);   // round-to-nearest-even
    return (unsigned short)(u >> 16);
}
__device__ __forceinline__ float bf2f(unsigned short u) {
    return __uint_as_float((unsigned)u << 16);
}

__device__ __forceinline__ floatx4 mfma32(bf16x8 a, bf16x8 b, floatx4 c) {
    return __builtin_amdgcn_mfma_f32_16x16x32_bf16(a, b, c, 0, 0, 0);
}
__device__ __forceinline__ floatx4 mfma16(short4v a, short4v b, floatx4 c) {
    return __builtin_amdgcn_mfma_f32_16x16x16bf16_1k(a, b, c, 0, 0, 0);
}

// ---------------- fp32 -> bf16 converts (hidden + all 4 weights, one launch) --------
__global__ __launch_bounds__(256) void cvt_all(
    const float* __restrict__ hidden,
    const float* __restrict__ Wq, const float* __restrict__ Wk,
    const float* __restrict__ Wv, const float* __restrict__ Wo,
    unsigned short* __restrict__ hid_bf,
    unsigned short* __restrict__ oqkv, unsigned short* __restrict__ oo)
{
    const float* src;
    unsigned short* dst;
    int i;
    if (blockIdx.x < 4096) {
        src = hidden; dst = hid_bf;
        i = blockIdx.x * 256 + threadIdx.x;          // < 1048576
    } else {
        int blk = (blockIdx.x - 4096) >> 9;
        src = (blk == 0) ? Wq : (blk == 1) ? Wk : (blk == 2) ? Wv : Wo;
        dst = (blk == 3) ? oo : oqkv + (size_t)blk * 1048576;
        i = ((blockIdx.x - 4096) & 511) * 256 + threadIdx.x;   // < 131072
    }
    const float4* p = (const float4*)src + (size_t)i * 2;
    float4 a = p[0], b = p[1];
    ushortx8 o;
    o[0] = f2bf(a.x); o[1] = f2bf(a.y); o[2] = f2bf(a.z); o[3] = f2bf(a.w);
    o[4] = f2bf(b.x); o[5] = f2bf(b.y); o[6] = f2bf(b.z); o[7] = f2bf(b.w);
    *((ushortx8*)dst + i) = o;
}

// ---------- shared BK=64 K-loop, 128x128 tile, swizzled LDS ----------
// LDS tile: 128 rows x 64 cols. Phys 16B-chunk p of row r holds logical chunk
// p^(r&7). Fragment read k-step s (k = s*32 + quad*8): phys = (s*4+quad)^(l16&7).
template<bool SWAP>
__device__ __forceinline__ void kloop_bk64(
    const unsigned short* __restrict__ Ag,
    const unsigned short* __restrict__ Wg,
    unsigned short* As, unsigned short* Bs,
    int wm, int wn, int l16, int quad, int t,
    floatx4 acc[4][4])
{
#pragma unroll 1
    for (int k0 = 0; k0 < 1024; k0 += 64) {
        __syncthreads();
#pragma unroll
        for (int i = 0; i < 4; i++) {
            ASYNC16(Ag + (size_t)i * 32 * 1024 + k0, As + i * 2048 + t * 8);
            ASYNC16(Wg + (size_t)i * 32 * 1024 + k0, Bs + i * 2048 + t * 8);
        }
        __syncthreads();
#pragma unroll
        for (int s = 0; s < 2; s++) {
            int pb = ((s * 4 + quad) ^ (l16 & 7)) * 8;
            bf16x8 af[4], bfr[4];
#pragma unroll
            for (int mt = 0; mt < 4; mt++)
                af[mt] = *(const bf16x8*)(As + (wm + mt * 16 + l16) * 64 + pb);
#pragma unroll
            for (int nt = 0; nt < 4; nt++)
                bfr[nt] = *(const bf16x8*)(Bs + (wn + nt * 16 + l16) * 64 + pb);
            if (SWAP) {
#pragma unroll
                for (int ft = 0; ft < 4; ft++)
#pragma unroll
                    for (int st = 0; st < 4; st++)
                        acc[ft][st] = mfma32(bfr[ft], af[st], acc[ft][st]);
            } else {
#pragma unroll
                for (int mt = 0; mt < 4; mt++)
#pragma unroll
                    for (int nt = 0; nt < 4; nt++)
                        acc[mt][nt] = mfma32(af[mt], bfr[nt], acc[mt][nt]);
            }
        }
    }
}

// ---------------- merged QKV GEMM (SWAP compute) ----------------
// grid (64, 24): y<8 Q (prescaled by QSCALE), y<16 K, else V (permuted [b,h,d,s']).
__global__ __launch_bounds__(256) void gemm_qkv(
    const unsigned short* __restrict__ A,   // [8192][1024] bf16
    const unsigned short* __restrict__ W,   // [Wq;Wk;Wv] [3072][1024]
    const float* __restrict__ bq, const float* __restrict__ bk, const float* __restrict__ bv,
    unsigned short* __restrict__ Qo, unsigned short* __restrict__ Ko,
    unsigned short* __restrict__ Vo)
{
    __shared__ unsigned short As[128 * 64];
    __shared__ unsigned short Bs[128 * 64];
    const int t = threadIdx.x;
    const int wave = t >> 6, lane = t & 63;
    const int quad = lane >> 4, l16 = lane & 15;
    const int wm = (wave >> 1) * 64, wn = (wave & 1) * 64;
    const int srow = t >> 3;
    const int scol = ((t & 7) ^ (srow & 7)) * 8;

    const unsigned short* Ag = A + ((size_t)blockIdx.x * 128 + srow) * 1024 + scol;
    const unsigned short* Wg = W + ((size_t)blockIdx.y * 128 + srow) * 1024 + scol;

    floatx4 acc[4][4] = {};
    kloop_bk64<true>(Ag, Wg, As, Bs, wm, wn, l16, quad, t, acc);

    int y = blockIdx.y;
    if (y < 16) {
        // Q/K: [b,h,s,d]; lane owns 4 consecutive d -> 8B stores. Q gets QSCALE.
        const float* bp = (y < 8) ? bq : bk;
        unsigned short* op = (y < 8) ? Qo : Ko;
        float sc = (y < 8) ? QSCALE : 1.0f;
#pragma unroll
        for (int ft = 0; ft < 4; ft++) {
            int featg = (y * 128 + wn + ft * 16 + quad * 4) & 1023;
            float4 b4 = *(const float4*)(bp + featg);
            int h = featg >> 6, d = featg & 63;
#pragma unroll
            for (int st = 0; st < 4; st++) {
                int sg = blockIdx.x * 128 + wm + st * 16 + l16;
                int b = sg >> 10, s = sg & 1023;
                ushortx4 o4;
                o4[0] = f2bf((acc[ft][st][0] + b4.x) * sc);
                o4[1] = f2bf((acc[ft][st][1] + b4.y) * sc);
                o4[2] = f2bf((acc[ft][st][2] + b4.z) * sc);
                o4[3] = f2bf((acc[ft][st][3] + b4.w) * sc);
                *(ushortx4*)(op + (((size_t)(b * 16 + h) * 1024 + s) * 64 + d)) = o4;
            }
        }
    } else {
        // V: [b,h,d,s'] with per-64-window PV-fragment permutation:
        // s = 64a + nt*16 + q*4 + j  ->  s' = 64a + (nt>>1)*32 + q*8 + (nt&1)*4 + j
#pragma unroll
        for (int ft = 0; ft < 4; ft++) {
            int featg = (y * 128 + wn + ft * 16 + quad * 4) & 1023;
            float4 b4 = *(const float4*)(bv + featg);
#pragma unroll
            for (int r = 0; r < 4; r++) {
                int feat = featg + r;
                int h = feat >> 6, d = feat & 63;
                float bias = (r == 0) ? b4.x : (r == 1) ? b4.y : (r == 2) ? b4.z : b4.w;
#pragma unroll
                for (int st = 0; st < 4; st++) {
                    int sg = blockIdx.x * 128 + wm + st * 16 + l16;
                    int b = sg >> 10, s = sg & 1023;
                    int sp = (s & ~63) + (st >> 1) * 32 + (l16 >> 2) * 8 + (st & 1) * 4 + (l16 & 3);
                    Vo[((size_t)(b * 16 + h) * 64 + d) * 1024 + sp] = f2bf(acc[ft][st][r] + bias);
                }
            }
        }
    }
}

// ---------------- flash attention: 128-row Q tile, direct-global Q fragments ----------
// grid (128, 8): x = head (id%8 = head%8 -> one head per XCD), y = 128-row q-tile.
// Wave w owns q rows 32w..32w+31 (two 16-groups qg). Q fragments loaded straight
// from global (wave-private, once per block) -> no Qs LDS, one less barrier,
// block LDS = 20.5 KB. K/V LDS reads amortize over 32 q-rows/wave (2x vs 64-row).
// All transients (kf, mk, v01/v23) kept loop-local to hold VGPR ~95 (r6 lesson).
__global__ __launch_bounds__(256) void attn(
    const unsigned short* __restrict__ Q,   // [b,h,s,d] (scaled by 0.125*log2e)
    const unsigned short* __restrict__ Kg,  // [b,h,s,d]
    const unsigned short* __restrict__ Vt,  // [b,h,d,s'] (permuted)
    const float* __restrict__ mask,         // [B][S]
    unsigned short* __restrict__ ctx)       // [B,S,H] bf16
{
    __shared__ unsigned short Ks[64 * 64];
    __shared__ unsigned short Vs[64 * 64];
    __shared__ float Msall[1024];

    const int t = threadIdx.x;
    const int wave = t >> 6, lane = t & 63, quad = lane >> 4, l16 = lane & 15;
    const int s7 = l16 & 7;
    const int head = blockIdx.x;
    const int b = head >> 4, h = head & 15;
    const int q0 = blockIdx.y * 128;
    const unsigned short* Qh = Q + (size_t)head * 65536;
    const unsigned short* Kh = Kg + (size_t)head * 65536;
    const unsigned short* Vh = Vt + (size_t)head * 65536;

    const int srow = t >> 3;
    const int scol = ((t & 7) ^ (srow & 7)) * 8;

    {   // mask row -> LDS, pre-scaled by log2e
        float4 m4 = *(const float4*)(mask + b * 1024 + t * 4);
        m4.x *= LOG2E; m4.y *= LOG2E; m4.z *= LOG2E; m4.w *= LOG2E;
        *(float4*)(Msall + t * 4) = m4;
    }

    // Q fragments direct from global: qf[qg][s][j] = Q[q0+wave*32+qg*16+l16][s*32+quad*8+j]
    bf16x8 qf[2][2];
#pragma unroll
    for (int qg = 0; qg < 2; qg++) {
        const unsigned short* qp = Qh + (size_t)(q0 + wave * 32 + qg * 16 + l16) * 64 + quad * 8;
        qf[qg][0] = *(const bf16x8*)(qp);
        qf[qg][1] = *(const bf16x8*)(qp + 32);
    }

    float rs0 = 0.f, rs1 = 0.f;
    floatx4 o_acc[2][4] = {};   // [qg][dt]: O^T rows d = dt*16+quad*4+r, col q = l16

    for (int k0 = 0; k0 < 1024; k0 += 64) {
        __syncthreads();
#pragma unroll
        for (int i = 0; i < 2; i++) {
            ASYNC16(Kh + (size_t)(k0 + i * 32 + srow) * 64 + scol, Ks + i * 2048 + t * 8);
            ASYNC16(Vh + (size_t)(i * 32 + srow) * 1024 + k0 + scol, Vs + i * 2048 + t * 8);
        }
        __syncthreads();

        short4v pf0[4], pf1[4];
#pragma unroll
        for (int nt = 0; nt < 4; nt++) {
            int krow = nt * 16 + l16;
            bf16x8 kf0 = *(const bf16x8*)(Ks + krow * 64 + ((quad ^ s7) * 8));
            bf16x8 kf1 = *(const bf16x8*)(Ks + krow * 64 + (((4 + quad) ^ s7) * 8));
            floatx4 mk = *(const floatx4*)(Msall + k0 + nt * 16 + quad * 4);
            floatx4 z0 = {0.f, 0.f, 0.f, 0.f};
            z0 = mfma32(kf0, qf[0][0], z0);
            z0 = mfma32(kf1, qf[0][1], z0);
            floatx4 z1 = {0.f, 0.f, 0.f, 0.f};
            z1 = mfma32(kf0, qf[1][0], z1);
            z1 = mfma32(kf1, qf[1][1], z1);
#pragma unroll
            for (int r = 0; r < 4; r++) {
                float p0 = exp2f(z0[r] + mk[r]);
                float p1 = exp2f(z1[r] + mk[r]);
                rs0 += p0;
                rs1 += p1;
                pf0[nt][r] = (short)(__float_as_uint(p0) >> 16);
                pf1[nt][r] = (short)(__float_as_uint(p1) >> 16);
            }
        }

        // O^T += V^T P^T; Vs permuted so (nt,nt+1) fragments are one b128 read.
        // vf loaded once per dt, reused by both q-groups.
#pragma unroll
        for (int dt = 0; dt < 4; dt++) {
            int vrow = dt * 16 + l16;
            ushortx8 v01 = *(const ushortx8*)(Vs + vrow * 64 + ((quad ^ s7) * 8));
            ushortx8 v23 = *(const ushortx8*)(Vs + vrow * 64 + (((4 + quad) ^ s7) * 8));
            short4v vf0 = {(short)v01[0], (short)v01[1], (short)v01[2], (short)v01[3]};
            short4v vf1 = {(short)v01[4], (short)v01[5], (short)v01[6], (short)v01[7]};
            short4v vf2 = {(short)v23[0], (short)v23[1], (short)v23[2], (short)v23[3]};
            short4v vf3 = {(short)v23[4], (short)v23[5], (short)v23[6], (short)v23[7]};
            o_acc[0][dt] = mfma16(vf0, pf0[0], o_acc[0][dt]);
            o_acc[0][dt] = mfma16(vf1, pf0[1], o_acc[0][dt]);
            o_acc[0][dt] = mfma16(vf2, pf0[2], o_acc[0][dt]);
            o_acc[0][dt] = mfma16(vf3, pf0[3], o_acc[0][dt]);
            o_acc[1][dt] = mfma16(vf0, pf1[0], o_acc[1][dt]);
            o_acc[1][dt] = mfma16(vf1, pf1[1], o_acc[1][dt]);
            o_acc[1][dt] = mfma16(vf2, pf1[2], o_acc[1][dt]);
            o_acc[1][dt] = mfma16(vf3, pf1[3], o_acc[1][dt]);
        }
    }

#pragma unroll
    for (int qg = 0; qg < 2; qg++) {
        float v = (qg == 0) ? rs0 : rs1;
        v += __shfl_xor(v, 16);
        v += __shfl_xor(v, 32);
        float inv_l = 1.0f / v;
        int qrow = q0 + wave * 32 + qg * 16 + l16;
#pragma unroll
        for (int dt = 0; dt < 4; dt++) {
            ushortx4 o4;
#pragma unroll
            for (int r = 0; r < 4; r++) o4[r] = f2bf(o_acc[qg][dt][r] * inv_l);
            *(ushortx4*)(ctx + ((size_t)(b * 1024 + qrow)) * 1024 + h * 64 + dt * 16 + quad * 4) = o4;
        }
    }
}

// ---------------- out-proj GEMM + bias + bf16 residual -> x (bf16) ----------------
__global__ __launch_bounds__(256) void gemm_proj(
    const unsigned short* __restrict__ A,   // ctx bf16 [8192][1024]
    const unsigned short* __restrict__ W,   // Wo bf16 [1024][1024]
    const float* __restrict__ bo,
    const unsigned short* __restrict__ resid,  // hid_bf [8192][1024]
    unsigned short* __restrict__ X)         // bf16 [8192][1024]
{
    __shared__ unsigned short As[128 * 64];
    __shared__ unsigned short Bs[128 * 64];
    const int t = threadIdx.x;
    const int wave = t >> 6, lane = t & 63;
    const int quad = lane >> 4, l16 = lane & 15;
    const int wm = (wave >> 1) * 64, wn = (wave & 1) * 64;
    const int srow = t >> 3;
    const int scol = ((t & 7) ^ (srow & 7)) * 8;

    const unsigned short* Ag = A + ((size_t)blockIdx.x * 128 + srow) * 1024 + scol;
    const unsigned short* Wg = W + ((size_t)blockIdx.y * 128 + srow) * 1024 + scol;

    floatx4 acc[4][4] = {};
    kloop_bk64<false>(Ag, Wg, As, Bs, wm, wn, l16, quad, t, acc);

#pragma unroll
    for (int nt = 0; nt < 4; nt++) {
        int gn = blockIdx.y * 128 + wn + nt * 16 + l16;
        float bias = bo[gn];
#pragma unroll
        for (int mt = 0; mt < 4; mt++) {
#pragma unroll
            for (int r = 0; r < 4; r++) {
                int gm = blockIdx.x * 128 + wm + mt * 16 + quad * 4 + r;
                size_t off = (size_t)gm * 1024 + gn;
                X[off] = f2bf(acc[mt][nt][r] + bias + bf2f(resid[off]));
            }
        }
    }
}

// ---------------- LayerNorm: one block per token row (bf16 in, fp32 out) ------------
__global__ __launch_bounds__(256) void ln_k(const unsigned short* __restrict__ X,
                                            const float* __restrict__ g,
                                            const float* __restrict__ be,
                                            float* __restrict__ out)
{
    int row = blockIdx.x;
    int t = threadIdx.x;
    const unsigned short* xr = X + (size_t)row * 1024;
    ushortx4 xb = *(const ushortx4*)(xr + t * 4);
    float4 v;
    v.x = bf2f(xb[0]);
    v.y = bf2f(xb[1]);
    v.z = bf2f(xb[2]);
    v.w = bf2f(xb[3]);
    float s = v.x + v.y + v.z + v.w;
    float ss = v.x * v.x + v.y * v.y + v.z * v.z + v.w * v.w;
    for (int off = 1; off < 64; off <<= 1) {
        s += __shfl_xor(s, off);
        ss += __shfl_xor(ss, off);
    }
    __shared__ float red[8];
    int wave = t >> 6, lane = t & 63;
    if (lane == 0) { red[wave] = s; red[4 + wave] = ss; }
    __syncthreads();
    s = red[0] + red[1] + red[2] + red[3];
    ss = red[4] + red[5] + red[6] + red[7];
    float mu = s * (1.f / 1024.f);
    float var = ss * (1.f / 1024.f) - mu * mu;
    float inv = rsqrtf(var + 1e-12f);
    float4 gv = *(const float4*)(g + t * 4);
    float4 bv = *(const float4*)(be + t * 4);
    float4 o;
    o.x = (v.x - mu) * inv * gv.x + bv.x;
    o.y = (v.y - mu) * inv * gv.y + bv.y;
    o.z = (v.z - mu) * inv * gv.z + bv.z;
    o.w = (v.w - mu) * inv * gv.w + bv.w;
    *(float4*)(out + (size_t)row * 1024 + t * 4) = o;
}

extern "C" void kernel_launch(void* const* d_in, const int* in_sizes, int n_in,
                              void* d_out, int out_size, void* d_ws, size_t ws_size,
                              hipStream_t stream)
{
    const float* hidden = (const float*)d_in[0];
    const float* mask   = (const float*)d_in[1];
    const float* Wq = (const float*)d_in[2];
    const float* bq = (const float*)d_in[3];
    const float* Wk = (const float*)d_in[4];
    const float* bk = (const float*)d_in[5];
    const float* Wv = (const float*)d_in[6];
    const float* bv = (const float*)d_in[7];
    const float* Wo = (const float*)d_in[8];
    const float* bo = (const float*)d_in[9];
    const float* gamma = (const float*)d_in[10];
    const float* beta  = (const float*)d_in[11];
    float* out = (float*)d_out;

    char* ws = (char*)d_ws;
    // layout (bytes): hid_bf 16M | wqkv_bf 6M | wo_bf 2M | vt_bf 16M | ctx_bf 16M | q_bf 16M | k_bf 16M
    // x (bf16, 16M) aliases q_bf (dead after attn). total 88M.
    unsigned short* hid_bf  = (unsigned short*)(ws + 0);
    unsigned short* wqkv_bf = (unsigned short*)(ws + 16777216);
    unsigned short* wo_bf   = (unsigned short*)(ws + 23068672);
    unsigned short* vt_bf   = (unsigned short*)(ws + 25165824);
    unsigned short* ctx_bf  = (unsigned short*)(ws + 41943040);
    unsigned short* q_bf    = (unsigned short*)(ws + 58720256);
    unsigned short* k_bf    = (unsigned short*)(ws + 75497472);
    unsigned short* x_bf    = (unsigned short*)(ws + 58720256);

    cvt_all<<<6144, 256, 0, stream>>>(hidden, Wq, Wk, Wv, Wo, hid_bf, wqkv_bf, wo_bf);

    gemm_qkv<<<dim3(64, 24), 256, 0, stream>>>(hid_bf, wqkv_bf, bq, bk, bv, q_bf, k_bf, vt_bf);
    attn<<<dim3(128, 8), 256, 0, stream>>>(q_bf, k_bf, vt_bf, mask, ctx_bf);
    gemm_proj<<<dim3(64, 8), 256, 0, stream>>>(ctx_bf, wo_bf, bo, hid_bf, x_bf);
    ln_k<<<8192, 256, 0, stream>>>(x_bf, gamma, beta, out);
}